// Round 1
// baseline (875.644 us; speedup 1.0000x reference)
//
#include <hip/hip_runtime.h>
#include <hip/hip_bf16.h>
#include <stdint.h>

typedef __bf16 bf16_t;
typedef __bf16 bf16x4 __attribute__((ext_vector_type(4)));
typedef __bf16 bf16x8 __attribute__((ext_vector_type(8)));
typedef float  f32x4  __attribute__((ext_vector_type(4)));

#define AS_G __attribute__((address_space(1)))
#define AS_L __attribute__((address_space(3)))

// ---------------- fp32 -> bf16 cast (vectorized, exact-cover grid) ----------------
__global__ void cast_f32_bf16(const float* __restrict__ src, bf16_t* __restrict__ dst) {
    int i = blockIdx.x * 256 + threadIdx.x;          // each thread: 4 elements
    float4 v = ((const float4*)src)[i];
    bf16x4 o;
    o.x = (bf16_t)v.x; o.y = (bf16_t)v.y; o.z = (bf16_t)v.z; o.w = (bf16_t)v.w;
    ((bf16x4*)dst)[i] = o;
}

// ---------------- bf16 GEMM: C[M,N] = A[M,K] * Bt[N,K]^T + bias ----------------
// 128x128 tile, BK=32, 256 threads = 4 waves (2x2), each wave 64x64 via 4x4 MFMA 16x16x32.
// m97 structure: global_load_lds width=16 staging, unpadded LDS tiles.
template<int OUT_BF16>
__global__ void gemm_bt_kernel(const bf16_t* __restrict__ A,
                               const bf16_t* __restrict__ Bt,
                               const float* __restrict__ bias,
                               void* __restrict__ Cout,
                               int M, int N, int K) {
    __shared__ bf16_t As[128 * 32];
    __shared__ bf16_t Bs[128 * 32];
    const int tid  = threadIdx.x;
    const int wave = tid >> 6, lane = tid & 63;
    const int quad = lane >> 4, r16 = lane & 15;
    const int wm = (wave >> 1) * 64, wn = (wave & 1) * 64;
    const int m0 = blockIdx.y * 128, n0 = blockIdx.x * 128;

    // staging: wave w stages A rows [w*32, w*32+32) and B rows likewise, 2 instrs each
    const int sr = (wave << 5) + (lane >> 2);   // row for first instr
    const int ce = (lane & 3) << 3;             // k-element offset (8 bf16 = 16B)
    const bf16_t* ga = A  + (size_t)(m0 + sr) * K + ce;
    const bf16_t* gb = Bt + (size_t)(n0 + sr) * K + ce;
    bf16_t* la = &As[sr * 32 + ce];
    bf16_t* lb = &Bs[sr * 32 + ce];

    f32x4 acc[4][4] = {};

    for (int k0 = 0; k0 < K; k0 += 32) {
        __builtin_amdgcn_global_load_lds((AS_G void*)(ga + k0),              (AS_L void*)la,             16, 0, 0);
        __builtin_amdgcn_global_load_lds((AS_G void*)(ga + k0 + 16 * (size_t)K), (AS_L void*)(la + 16 * 32), 16, 0, 0);
        __builtin_amdgcn_global_load_lds((AS_G void*)(gb + k0),              (AS_L void*)lb,             16, 0, 0);
        __builtin_amdgcn_global_load_lds((AS_G void*)(gb + k0 + 16 * (size_t)K), (AS_L void*)(lb + 16 * 32), 16, 0, 0);
        __syncthreads();

        bf16x8 aF[4], bF[4];
#pragma unroll
        for (int t = 0; t < 4; ++t) {
            aF[t] = *(const bf16x8*)&As[(wm + t * 16 + r16) * 32 + quad * 8];
            bF[t] = *(const bf16x8*)&Bs[(wn + t * 16 + r16) * 32 + quad * 8];
        }
#pragma unroll
        for (int tm = 0; tm < 4; ++tm)
#pragma unroll
            for (int tn = 0; tn < 4; ++tn)
                acc[tm][tn] = __builtin_amdgcn_mfma_f32_16x16x32_bf16(aF[tm], bF[tn], acc[tm][tn], 0, 0, 0);
        __syncthreads();
    }

    float bv[4];
#pragma unroll
    for (int tn = 0; tn < 4; ++tn) bv[tn] = bias[n0 + wn + tn * 16 + r16];

#pragma unroll
    for (int tm = 0; tm < 4; ++tm) {
#pragma unroll
        for (int r = 0; r < 4; ++r) {
            const int m = m0 + wm + tm * 16 + quad * 4 + r;
#pragma unroll
            for (int tn = 0; tn < 4; ++tn) {
                const int n = n0 + wn + tn * 16 + r16;
                const float v = acc[tm][tn][r] + bv[tn];
                if (OUT_BF16) ((bf16_t*)Cout)[(size_t)m * N + n] = (bf16_t)v;
                else          ((float*)Cout)[(size_t)m * N + n]  = v;
            }
        }
    }
}

// ---------------- attention: one wave per (b,a) position ----------------
// scores (16x16) = QK^T/12 via 2 MFMAs from global; sparsemax over g (16) via
// per-lane bitonic network; PV via zero-padded MFMA per 16-wide e-chunk; write
// into M2 with the torch transpose(1,2).view(B,-1,D) scramble folded in:
//   r = h*256 + a>>4, c = (a&15)*64 + e, m2 = r*8 + b.
__global__ void attn_kernel(const bf16_t* __restrict__ Q, const bf16_t* __restrict__ K,
                            const bf16_t* __restrict__ V, bf16_t* __restrict__ M2) {
    __shared__ float zs_s[4][16][17];
    __shared__ float tau_s[4][16];
    const int wave = threadIdx.x >> 6, lane = threadIdx.x & 63;
    const int quad = lane >> 4, g16 = lane & 15;
    const int p = blockIdx.x * 4 + wave;        // p = a*8 + b  (row index of Q/K/V)
    const int a = p >> 3, b = p & 7;
    const bf16_t* q = Q + (size_t)p * 1024;
    const bf16_t* k = K + (size_t)p * 1024;
    const bf16_t* v = V + (size_t)p * 1024;

    // QK^T: A-frag = Q[h=lane&15][k=quad*8+j], B-frag = K[g=lane&15][k=quad*8+j]
    bf16x8 qa0 = *(const bf16x8*)(q + g16 * 64 + quad * 8);
    bf16x8 qa1 = *(const bf16x8*)(q + g16 * 64 + 32 + quad * 8);
    bf16x8 ka0 = *(const bf16x8*)(k + g16 * 64 + quad * 8);
    bf16x8 ka1 = *(const bf16x8*)(k + g16 * 64 + 32 + quad * 8);
    f32x4 sc = {0.f, 0.f, 0.f, 0.f};
    sc = __builtin_amdgcn_mfma_f32_16x16x32_bf16(qa0, ka0, sc, 0, 0, 0);
    sc = __builtin_amdgcn_mfma_f32_16x16x32_bf16(qa1, ka1, sc, 0, 0, 0);

    const float inv = 1.0f / 12.0f;  // 1/(sqrt(64) * alpha=1.5)
#pragma unroll
    for (int r = 0; r < 4; ++r) zs_s[wave][quad * 4 + r][g16] = sc[r] * inv;   // row h=quad*4+r, col g=lane&15
    __syncthreads();

    if (lane < 16) {   // lane = row h; serial sparsemax on 16 values (all constant-indexed -> VGPRs)
        float z[16];
#pragma unroll
        for (int j = 0; j < 16; ++j) z[j] = zs_s[wave][lane][j];
        // bitonic sort, descending
#pragma unroll
        for (int kk = 2; kk <= 16; kk <<= 1) {
#pragma unroll
            for (int j = kk >> 1; j > 0; j >>= 1) {
#pragma unroll
                for (int i = 0; i < 16; ++i) {
                    int ixj = i ^ j;
                    if (ixj > i) {
                        bool desc = ((i & kk) == 0);
                        float zi = z[i], zj = z[ixj];
                        bool sw = desc ? (zi < zj) : (zi > zj);
                        z[i]   = sw ? zj : zi;
                        z[ixj] = sw ? zi : zj;
                    }
                }
            }
        }
        float cum = 0.f, csel = 0.f;
        int ksel = 1;
#pragma unroll
        for (int j = 0; j < 16; ++j) {
            cum += z[j];
            bool sup = z[j] * (float)(j + 1) > (cum - 1.0f);   // z_sorted - (cumsum-1)/r > 0
            ksel = sup ? (j + 1) : ksel;
            csel = sup ? cum : csel;
        }
        tau_s[wave][lane] = (csel - 1.0f) / (float)ksel;
    }
    __syncthreads();

    // attn = max(zs - tau[h], 0), stored [h][g] for A-frag reads
#pragma unroll
    for (int r = 0; r < 4; ++r) {
        float av = sc[r] * inv - tau_s[wave][quad * 4 + r];
        zs_s[wave][quad * 4 + r][g16] = av > 0.f ? av : 0.f;
    }
    __syncthreads();

    // PV: A-frag attn[m=lane&15][k=quad*8+j], k>=16 -> 0 (quads 2,3)
    bf16x8 aP;
#pragma unroll
    for (int j = 0; j < 8; ++j) {
        float f = (quad < 2) ? zs_s[wave][g16][quad * 8 + j] : 0.f;
        aP[j] = (bf16_t)f;
    }
#pragma unroll
    for (int c = 0; c < 4; ++c) {     // e-chunks of 16
        bf16x8 bV;
#pragma unroll
        for (int j = 0; j < 8; ++j) {  // B-frag: V[k=g=quad*8+j][n=e0+lane&15], g>=16 -> 0
            int g = quad * 8 + j;
            bV[j] = (quad < 2) ? v[g * 64 + c * 16 + g16] : (bf16_t)0.f;
        }
        f32x4 oc = {0.f, 0.f, 0.f, 0.f};
        oc = __builtin_amdgcn_mfma_f32_16x16x32_bf16(aP, bV, oc, 0, 0, 0);
#pragma unroll
        for (int r = 0; r < 4; ++r) {
            int h = quad * 4 + r;
            int e = c * 16 + g16;
            int rr = (h << 8) + (a >> 4);
            int c2 = ((a & 15) << 6) + e;
            M2[((size_t)(rr * 8 + b)) * 1024 + c2] = (bf16_t)oc[r];
        }
    }
}

// ---------------- launch ----------------
extern "C" void kernel_launch(void* const* d_in, const int* in_sizes, int n_in,
                              void* d_out, int out_size, void* d_ws, size_t ws_size,
                              hipStream_t stream) {
    (void)in_sizes; (void)n_in; (void)out_size; (void)ws_size;
    const float* query = (const float*)d_in[0];
    const float* key   = (const float*)d_in[1];
    const float* value = (const float*)d_in[2];
    const float* Wq = (const float*)d_in[3];
    const float* bq = (const float*)d_in[4];
    const float* Wk = (const float*)d_in[5];
    const float* bk = (const float*)d_in[6];
    const float* Wv = (const float*)d_in[7];
    const float* bv = (const float*)d_in[8];
    const float* Wo = (const float*)d_in[9];
    const float* bo = (const float*)d_in[10];

    const int M = 32768, D = 1024;
    const size_t MD = (size_t)M * D;

    uint8_t* ws = (uint8_t*)d_ws;
    bf16_t* abuf = (bf16_t*)ws;                 // reused cast buffer (64 MiB)
    bf16_t* Qb   = (bf16_t*)(ws + MD * 2);
    bf16_t* Kb   = Qb + MD;
    bf16_t* Vb   = Kb + MD;
    bf16_t* M2   = Vb + MD;
    bf16_t* Wqb  = M2 + MD;
    bf16_t* Wkb  = Wqb + (size_t)D * D;
    bf16_t* Wvb  = Wkb + (size_t)D * D;
    bf16_t* Wob  = Wvb + (size_t)D * D;

    const int wBlocks = D * D / 1024;           // 1024
    const int aBlocks = (int)(MD / 1024);       // 32768
    cast_f32_bf16<<<wBlocks, 256, 0, stream>>>(Wq, Wqb);
    cast_f32_bf16<<<wBlocks, 256, 0, stream>>>(Wk, Wkb);
    cast_f32_bf16<<<wBlocks, 256, 0, stream>>>(Wv, Wvb);
    cast_f32_bf16<<<wBlocks, 256, 0, stream>>>(Wo, Wob);

    dim3 gg(D / 128, M / 128);                  // (8, 256)

    cast_f32_bf16<<<aBlocks, 256, 0, stream>>>(query, abuf);
    gemm_bt_kernel<1><<<gg, 256, 0, stream>>>(abuf, Wqb, bq, Qb, M, D, D);
    cast_f32_bf16<<<aBlocks, 256, 0, stream>>>(key, abuf);
    gemm_bt_kernel<1><<<gg, 256, 0, stream>>>(abuf, Wkb, bk, Kb, M, D, D);
    cast_f32_bf16<<<aBlocks, 256, 0, stream>>>(value, abuf);
    gemm_bt_kernel<1><<<gg, 256, 0, stream>>>(abuf, Wvb, bv, Vb, M, D, D);

    attn_kernel<<<M / 4, 256, 0, stream>>>(Qb, Kb, Vb, M2);

    gemm_bt_kernel<0><<<gg, 256, 0, stream>>>(M2, Wob, bo, (float*)d_out, M, D, D);
}